// Round 7
// baseline (368.283 us; speedup 1.0000x reference)
//
#include <hip/hip_runtime.h>
#include <cstdint>
#include <cstddef>

// Problem constants
#define BB   2
#define SS   1024
#define HID  2048
#define HH   32
#define KVHH 8
#define DD   64
#define NQKV 3072   // fused QKV projection width: 2048 q + 512 k + 512 v
#define QKW  2560   // qk_bf row width: 2048 q + 512 k

typedef __attribute__((ext_vector_type(8))) short bf16x8;
typedef __attribute__((ext_vector_type(4))) float f32x4;

__device__ __forceinline__ unsigned short f2bf(float f) {
    unsigned int u = __float_as_uint(f);
    unsigned int r = (u + 0x7fffu + ((u >> 16) & 1u)) >> 16;
    return (unsigned short)r;
}

// async global->LDS 16B (wave-uniform LDS base + lane*16 layout required)
__device__ __forceinline__ void g2l16(const unsigned short* g, unsigned short* l) {
    __builtin_amdgcn_global_load_lds(
        (__attribute__((address_space(1))) void*)(unsigned short*)g,
        (__attribute__((address_space(3))) void*)l,
        16, 0, 0);
}

// ---------------------------------------------------------------------------
// prep: z=0..3 weight transpose+convert; z=4 hidden fp32->bf16.
// ---------------------------------------------------------------------------
__global__ void prep(const float* __restrict__ hidden,
                     const float* __restrict__ Wq, const float* __restrict__ Wk,
                     const float* __restrict__ Wv, const float* __restrict__ Wo,
                     unsigned short* __restrict__ hidden_bf,
                     unsigned short* __restrict__ WqkvT,
                     unsigned short* __restrict__ WoT)
{
    const int z  = blockIdx.z;
    const int tx = threadIdx.x, ty = threadIdx.y;

    if (z == 4) {
        int r0 = blockIdx.y * 32, c0 = blockIdx.x * 32;
        #pragma unroll
        for (int i = 0; i < 4; ++i) {
            int row = r0 + ty * 4 + i;
            hidden_bf[(size_t)row * 2048 + c0 + tx] =
                f2bf(hidden[(size_t)row * 2048 + c0 + tx]);
        }
        return;
    }

    const float* W;
    unsigned short* Wt;
    int N;
    if (z == 0)      { W = Wq; Wt = WqkvT;                        N = 2048; }
    else if (z == 1) { W = Wk; Wt = WqkvT + (size_t)2048 * 2048;  N = 512;  }
    else if (z == 2) { W = Wv; Wt = WqkvT + (size_t)2560 * 2048;  N = 512;  }
    else             { W = Wo; Wt = WoT;                          N = 2048; }
    if (blockIdx.x * 32 >= N) return;

    __shared__ float t[32][33];
    const int n0 = blockIdx.x * 32, k0 = blockIdx.y * 32;
    #pragma unroll
    for (int i = 0; i < 4; ++i)
        t[ty * 4 + i][tx] = W[(size_t)(k0 + ty * 4 + i) * N + n0 + tx];
    __syncthreads();
    #pragma unroll
    for (int i = 0; i < 4; ++i)
        Wt[(size_t)(n0 + ty * 4 + i) * 2048 + k0 + tx] = f2bf(t[tx][ty * 4 + i]);
}

// ---------------------------------------------------------------------------
// bf16 MFMA GEMM, B-transposed, async global_load_lds staging (m97 pattern).
// C(MxN fp32) = A(MxK bf16) @ Bt(NxK bf16)^T. 128x128 tile, BK=32.
// ---------------------------------------------------------------------------
__global__ __launch_bounds__(256) void gemm_bf16_bt(
    const unsigned short* __restrict__ A,
    const unsigned short* __restrict__ Bt,
    float* __restrict__ C, int M, int N, int K)
{
    __shared__ short As[128][32];
    __shared__ short Bs[128][32];

    const int tid  = threadIdx.x;
    const int lane = tid & 63;
    const int wave = tid >> 6;
    const int wm = (wave >> 1) * 64, wn = (wave & 1) * 64;
    const int m0 = blockIdx.y * 128, n0 = blockIdx.x * 128;

    f32x4 acc[4][4] = {};

    const int mrow = lane & 15;
    const int kq   = (lane >> 4) * 8;

    for (int k0 = 0; k0 < K; k0 += 32) {
        #pragma unroll
        for (int p = 0; p < 2; ++p) {
            int ci = tid + p * 256;           // 0..511, lane-contiguous per wave
            int row = ci >> 2;
            int q = (ci & 3) * 8;
            g2l16(&A [(size_t)(m0 + row) * K + k0 + q], (unsigned short*)&As[0][0] + ci * 8);
            g2l16(&Bt[(size_t)(n0 + row) * K + k0 + q], (unsigned short*)&Bs[0][0] + ci * 8);
        }
        __syncthreads();

        bf16x8 af[4], bfr[4];
        #pragma unroll
        for (int i = 0; i < 4; ++i)
            af[i] = *(const bf16x8*)&As[wm + i * 16 + mrow][kq];
        #pragma unroll
        for (int j = 0; j < 4; ++j)
            bfr[j] = *(const bf16x8*)&Bs[wn + j * 16 + mrow][kq];

        #pragma unroll
        for (int i = 0; i < 4; ++i)
            #pragma unroll
            for (int j = 0; j < 4; ++j)
                acc[i][j] = __builtin_amdgcn_mfma_f32_16x16x32_bf16(
                    af[i], bfr[j], acc[i][j], 0, 0, 0);
        __syncthreads();
    }

    #pragma unroll
    for (int i = 0; i < 4; ++i) {
        int grow = m0 + wm + i * 16 + (lane >> 4) * 4;
        #pragma unroll
        for (int j = 0; j < 4; ++j) {
            int gcol = n0 + wn + j * 16 + (lane & 15);
            #pragma unroll
            for (int rg = 0; rg < 4; ++rg)
                C[(size_t)(grow + rg) * N + gcol] = acc[i][j][rg];
        }
    }
}

// ---------------------------------------------------------------------------
// postproc: { rope q/k -> qk_bf bf16 } + { v transpose -> v_t bf16 }.
// ---------------------------------------------------------------------------
__global__ void postproc(const float* __restrict__ qkv,
                         unsigned short* __restrict__ qk_bf,
                         unsigned short* __restrict__ v_t)
{
    const int gb = blockIdx.x;
    if (gb < 10240) {
        const int r = gb >> 8;
        const int t = threadIdx.x & 31;
        const int row = (gb & 255) * 8 + (threadIdx.x >> 5);
        const int s = row & (SS - 1);

        const float* src = qkv + (size_t)row * NQKV + r * 64;
        unsigned short* dst = qk_bf + (size_t)row * QKW + r * 64;

        float x1 = src[t];
        float x2 = src[t + 32];
        float inv = powf(10000.f, -(float)t * (1.f / 32.f));
        float ang = (float)s * inv;
        float c, sn;
        sincosf(ang, &sn, &c);
        float scale = (r < 32) ? 0.125f : 1.0f;
        dst[t]      = f2bf((x1 * c - x2 * sn) * scale);
        dst[t + 32] = f2bf((x2 * c + x1 * sn) * scale);
    } else {
        __shared__ float tls[32][33];
        const int id = gb - 10240;
        const int cblk = id & 15;
        const int sblk = (id >> 4) & 31;
        const int b    = id >> 9;
        const int c0 = cblk * 32, s0 = sblk * 32;
        const int tx = threadIdx.x & 31, ty = threadIdx.x >> 5;
        #pragma unroll
        for (int i = 0; i < 4; ++i)
            tls[ty * 4 + i][tx] =
                qkv[(size_t)(b * SS + s0 + ty * 4 + i) * NQKV + 2560 + c0 + tx];
        __syncthreads();
        #pragma unroll
        for (int i = 0; i < 4; ++i)
            v_t[(size_t)(b * 512 + c0 + ty * 4 + i) * SS + s0 + tx] =
                f2bf(tls[tx][ty * 4 + i]);
    }
}

// ---------------------------------------------------------------------------
// Chunk decode: blockIdx.x in [0,40): big-qt first. Returns (qt, chunk).
// nchunk(qt) = ceil((qt+1)/4); sum over qt=0..15 is 40.
// ---------------------------------------------------------------------------
__device__ __forceinline__ void decode_chunk(int bx, int& qt, int& c) {
    int x = 39 - bx;
    int t = 0, acc = 0;
    for (;;) { int n = (t + 4) >> 2; if (x < acc + n) break; acc += n; ++t; }
    qt = t; c = x - acc;
}

// ---------------------------------------------------------------------------
// attn_l: partial softmax denominators per k-chunk (4 k-tiles of 64).
// Grid (40, 8 kh, 2 b); block 256 = 4 waves = 4 heads of the GQA group.
// Writes l_part[((b*32+h)*4 + chunk)*1024 + q] (each slot written once).
// ---------------------------------------------------------------------------
__global__ __launch_bounds__(256) void attn_l(
    const unsigned short* __restrict__ qk_bf,
    const float* __restrict__ bias_diag,
    float* __restrict__ l_part)
{
    int qt, c;
    decode_chunk(blockIdx.x, qt, c);
    const int kh = blockIdx.y, b = blockIdx.z;
    const int wave = threadIdx.x >> 6, lane = threadIdx.x & 63;
    const int quad = lane >> 4, l15 = lane & 15;
    const int h  = kh * 4 + wave;
    const int q0 = qt * 64;
    const int j0 = c * 4;
    const int j1 = (j0 + 4 < qt + 1) ? j0 + 4 : qt + 1;
    const int kbase = j0 * 64;
    const int rmin  = q0 - kbase - 255;

    __shared__ float bdw_all[4][320];
    float* bdw = bdw_all[wave];
    for (int i = lane; i < 320; i += 64) {
        int rel = rmin + i;
        bdw[i] = ((unsigned)rel < 1024u) ? bias_diag[h * 1024 + rel] : 0.f;
    }

    bf16x8 Qf[4][2];
    const unsigned short* Qg = qk_bf + (size_t)(b * SS + q0) * QKW + h * 64;
    #pragma unroll
    for (int nq = 0; nq < 4; ++nq)
        #pragma unroll
        for (int s = 0; s < 2; ++s)
            Qf[nq][s] = *(const bf16x8*)&Qg[(size_t)(nq * 16 + l15) * QKW + s * 32 + quad * 8];

    const unsigned short* Kg = qk_bf + (size_t)(b * SS) * QKW + 2048 + kh * 64;

    float lp[4] = {0.f, 0.f, 0.f, 0.f};
    for (int j = j0; j < j1; ++j) {
        const int k0 = j * 64;
        bf16x8 Kf[4][2];
        #pragma unroll
        for (int nk = 0; nk < 4; ++nk)
            #pragma unroll
            for (int s = 0; s < 2; ++s)
                Kf[nk][s] = *(const bf16x8*)&Kg[(size_t)(k0 + nk * 16 + l15) * QKW + s * 32 + quad * 8];

        f32x4 st[4][4] = {};   // [nk][nq]: S^T tile, col q = l15, row kp
        #pragma unroll
        for (int s = 0; s < 2; ++s)
            #pragma unroll
            for (int nk = 0; nk < 4; ++nk)
                #pragma unroll
                for (int nq = 0; nq < 4; ++nq)
                    st[nk][nq] = __builtin_amdgcn_mfma_f32_16x16x32_bf16(
                        Kf[nk][s], Qf[nq][s], st[nk][nq], 0, 0, 0);

        const bool full = (j < qt);
        #pragma unroll
        for (int nk = 0; nk < 4; ++nk)
            #pragma unroll
            for (int nq = 0; nq < 4; ++nq) {
                int relb = (q0 + nq * 16 + l15) - (k0 + nk * 16 + quad * 4);
                #pragma unroll
                for (int r = 0; r < 4; ++r) {
                    int rel = relb - r;
                    if (full || rel >= 0)
                        lp[nq] += __expf(st[nk][nq][r] + bdw[rel - rmin]);
                }
            }
    }

    // butterfly over the 4 quads; then quad 0 stores
    #pragma unroll
    for (int nq = 0; nq < 4; ++nq) {
        lp[nq] += __shfl_xor(lp[nq], 16, 64);
        lp[nq] += __shfl_xor(lp[nq], 32, 64);
    }
    if (quad == 0) {
        #pragma unroll
        for (int nq = 0; nq < 4; ++nq)
            l_part[(size_t)((b * 32 + h) * 4 + c) * 1024 + q0 + nq * 16 + l15] = lp[nq];
    }
}

// ---------------------------------------------------------------------------
// attn_o: atomic-free PV pass. One block per (qtile, head, b) = 1024 blocks.
// 4 waves; wave w owns q-rows [q0+w*16, q0+w*16+16) of head h, covering the
// FULL k-range [0,(qt+1)*64). l is read from l_part (precomputed by attn_l).
// w = relu(exp(s+bias) - c*l); PV accumulated in registers; AO written once
// in bf16 (no atomics, no zero-init, no conversion pass).
// ---------------------------------------------------------------------------
__global__ __launch_bounds__(256) void attn_o(
    const unsigned short* __restrict__ qk_bf,
    const unsigned short* __restrict__ v_t,
    const float* __restrict__ bias_diag,
    const float* __restrict__ soff,
    const float* __restrict__ l_part,
    unsigned short* __restrict__ AO_bf)
{
    const int qt = 15 - (int)blockIdx.x;   // big tiles dispatched first
    const int h  = blockIdx.y;
    const int b  = blockIdx.z;
    const int kh = h >> 2;
    const int wave = threadIdx.x >> 6, lane = threadIdx.x & 63;
    const int quad = lane >> 4, l15 = lane & 15;
    const int q0 = qt * 64;
    const int qw0 = q0 + wave * 16;        // wave's 16 q-rows
    const int nch = (qt + 4) >> 2;

    __shared__ float bd[1024];             // shared: all 4 waves same head
    __shared__ short Ws_all[4][16][72];    // wave-private P stripe (16q x 64k)
    short (*Ws)[72] = Ws_all[wave];

    for (int i = threadIdx.x; i < 1024; i += 256) bd[i] = bias_diag[h * 1024 + i];
    __syncthreads();                       // only barrier in this kernel

    // Q fragments for the wave's 16 rows (held all kernel)
    bf16x8 Qf[2];
    const unsigned short* Qg = qk_bf + (size_t)(b * SS + qw0) * QKW + h * 64;
    #pragma unroll
    for (int s = 0; s < 2; ++s)
        Qf[s] = *(const bf16x8*)&Qg[(size_t)l15 * QKW + s * 32 + quad * 8];

    // lane's q-row = qw0 + l15: total l, then 1/l and c*l
    float invl, cl;
    {
        int q = qw0 + l15;
        float ssum = 0.f;
        for (int cc = 0; cc < nch; ++cc)
            ssum += l_part[(size_t)((b * 32 + h) * 4 + cc) * 1024 + q];
        invl = 1.f / ssum;
        cl = fabsf(soff[h] + 1.f) / (float)(q + 1) * ssum;
    }

    const unsigned short* Kg = qk_bf + (size_t)(b * SS) * QKW + 2048 + kh * 64;
    const unsigned short* Vg = v_t + (size_t)(b * 512 + kh * 64) * SS;

    f32x4 Oa[4] = {};                      // [nd]: rows q (quad*4+r), cols d
    for (int j = 0; j <= qt; ++j) {
        const int k0 = j * 64;
        bf16x8 Kf[4][2], Vf[4][2];
        #pragma unroll
        for (int nk = 0; nk < 4; ++nk)
            #pragma unroll
            for (int s = 0; s < 2; ++s)
                Kf[nk][s] = *(const bf16x8*)&Kg[(size_t)(k0 + nk * 16 + l15) * QKW + s * 32 + quad * 8];
        #pragma unroll
        for (int nd = 0; nd < 4; ++nd)
            #pragma unroll
            for (int cc = 0; cc < 2; ++cc)
                Vf[nd][cc] = *(const bf16x8*)&Vg[(size_t)(nd * 16 + l15) * SS + k0 + cc * 32 + quad * 8];

        // S^T (64k x 16q): col = q = l15, row = k_local = nk*16+quad*4+r
        f32x4 st[4] = {};
        #pragma unroll
        for (int s = 0; s < 2; ++s)
            #pragma unroll
            for (int nk = 0; nk < 4; ++nk)
                st[nk] = __builtin_amdgcn_mfma_f32_16x16x32_bf16(
                    Kf[nk][s], Qf[s], st[nk], 0, 0, 0);

        // w = relu(exp(s+bias) - c*l) -> Ws stripe (packed b64 stores)
        const bool full = (j < qt);
        #pragma unroll
        for (int nk = 0; nk < 4; ++nk) {
            int relb = (qw0 + l15) - (k0 + nk * 16 + quad * 4);
            ushort4 pk;
            #pragma unroll
            for (int r = 0; r < 4; ++r) {
                int rel = relb - r;
                float w = 0.f;
                if (full || rel >= 0)
                    w = fmaxf(__expf(st[nk][r] + bd[rel]) - cl, 0.f);
                ((unsigned short*)&pk)[r] = f2bf(w);
            }
            *(ushort4*)&Ws[l15][nk * 16 + quad * 4] = pk;
        }

        // PV: A = Ws rows (m=q), B = Vt rows (n=d), contraction over local k
        #pragma unroll
        for (int cc = 0; cc < 2; ++cc) {
            bf16x8 Wf = *(const bf16x8*)&Ws[l15][cc * 32 + quad * 8];
            #pragma unroll
            for (int nd = 0; nd < 4; ++nd)
                Oa[nd] = __builtin_amdgcn_mfma_f32_16x16x32_bf16(
                    Wf, Vf[nd][cc], Oa[nd], 0, 0, 0);
        }
    }

    // epilogue: /l and single bf16 store per element (no atomics)
    #pragma unroll
    for (int r = 0; r < 4; ++r) {
        float iv = __shfl(invl, quad * 4 + r, 64);
        int q = qw0 + quad * 4 + r;
        #pragma unroll
        for (int nd = 0; nd < 4; ++nd)
            AO_bf[(size_t)(b * SS + q) * 2048 + h * 64 + nd * 16 + l15] =
                f2bf(Oa[nd][r] * iv);
    }
}

// ---------------------------------------------------------------------------
extern "C" void kernel_launch(void* const* d_in, const int* in_sizes, int n_in,
                              void* d_out, int out_size, void* d_ws, size_t ws_size,
                              hipStream_t stream)
{
    const float* hidden    = (const float*)d_in[0];
    const float* Wq        = (const float*)d_in[2];
    const float* Wk        = (const float*)d_in[3];
    const float* Wv        = (const float*)d_in[4];
    const float* Wo        = (const float*)d_in[5];
    const float* bias_diag = (const float*)d_in[6];
    const float* soff      = (const float*)d_in[7];
    float* out = (float*)d_out;

    // Workspace aliasing (54.5 MB, proven footprint):
    //  A [0,20.97M): hidden_bf(8.39)+WqkvT(12.58) --dead after QKV gemm-->
    //                qk_bf[0,10.49M) + v_t[10.49M,12.58M) + AO_bf[12.58M,20.97M)
    //  B [20.97M,29.36M): WoT
    //  C [29.36M,54.53M): qkv fp32(25.17M) --dead after postproc-->
    //                l_part[46.14M,47.19M)
    char* wsb = (char*)d_ws;
    unsigned short* hidden_bf = (unsigned short*)wsb;
    unsigned short* WqkvT     = (unsigned short*)(wsb + (size_t)8388608);
    unsigned short* qk_bf     = (unsigned short*)wsb;
    unsigned short* v_t       = (unsigned short*)(wsb + (size_t)10485760);
    unsigned short* AO_bf     = (unsigned short*)(wsb + (size_t)12582912);
    unsigned short* WoT       = (unsigned short*)(wsb + (size_t)20971520);
    float*          qkv       = (float*)(wsb + (size_t)29360128);
    float*          l_part    = (float*)(wsb + (size_t)46137344);

    // 1. weight transposes + hidden convert
    prep<<<dim3(64, 64, 5), dim3(32, 8), 0, stream>>>(
        hidden, Wq, Wk, Wv, Wo, hidden_bf, WqkvT, WoT);

    // 2. fused QKV projection (fp32 out)
    gemm_bf16_bt<<<dim3(NQKV / 128, 2048 / 128), dim3(256), 0, stream>>>(
        hidden_bf, WqkvT, qkv, 2048, NQKV, 2048);

    // 3. rope+convert q,k and v transpose
    postproc<<<dim3(11264), dim3(256), 0, stream>>>(qkv, qk_bf, v_t);

    // 4. partial denominators (chunked, balanced)
    attn_l<<<dim3(40, KVHH, BB), dim3(256), 0, stream>>>(
        qk_bf, bias_diag, l_part);

    // 5. atomic-free PV pass -> AO_bf (written once, bf16)
    attn_o<<<dim3(16, HH, BB), dim3(256), 0, stream>>>(
        qk_bf, v_t, bias_diag, soff, l_part, AO_bf);

    // 6. output projection
    gemm_bf16_bt<<<dim3(2048 / 128, 2048 / 128), dim3(256), 0, stream>>>(
        AO_bf, WoT, out, 2048, 2048, 2048);
}

// Round 8
// 302.644 us; speedup vs baseline: 1.2169x; 1.2169x over previous
//
#include <hip/hip_runtime.h>
#include <cstdint>
#include <cstddef>

// Problem constants
#define BB   2
#define SS   1024
#define HID  2048
#define HH   32
#define KVHH 8
#define DD   64
#define NQKV 3072   // fused QKV projection width: 2048 q + 512 k + 512 v
#define QKW  2560   // qk_bf row width: 2048 q + 512 k

typedef __attribute__((ext_vector_type(8))) short bf16x8;
typedef __attribute__((ext_vector_type(4))) float f32x4;

__device__ __forceinline__ unsigned short f2bf(float f) {
    unsigned int u = __float_as_uint(f);
    unsigned int r = (u + 0x7fffu + ((u >> 16) & 1u)) >> 16;
    return (unsigned short)r;
}

// async global->LDS 16B (wave-uniform LDS base + lane*16 layout required)
__device__ __forceinline__ void g2l16(const unsigned short* g, unsigned short* l) {
    __builtin_amdgcn_global_load_lds(
        (__attribute__((address_space(1))) void*)(unsigned short*)g,
        (__attribute__((address_space(3))) void*)l,
        16, 0, 0);
}

// ---------------------------------------------------------------------------
// prep: z=0..3 weight transpose+convert; z=4 hidden fp32->bf16.
// ---------------------------------------------------------------------------
__global__ void prep(const float* __restrict__ hidden,
                     const float* __restrict__ Wq, const float* __restrict__ Wk,
                     const float* __restrict__ Wv, const float* __restrict__ Wo,
                     unsigned short* __restrict__ hidden_bf,
                     unsigned short* __restrict__ WqkvT,
                     unsigned short* __restrict__ WoT)
{
    const int z  = blockIdx.z;
    const int tx = threadIdx.x, ty = threadIdx.y;

    if (z == 4) {
        int r0 = blockIdx.y * 32, c0 = blockIdx.x * 32;
        #pragma unroll
        for (int i = 0; i < 4; ++i) {
            int row = r0 + ty * 4 + i;
            hidden_bf[(size_t)row * 2048 + c0 + tx] =
                f2bf(hidden[(size_t)row * 2048 + c0 + tx]);
        }
        return;
    }

    const float* W;
    unsigned short* Wt;
    int N;
    if (z == 0)      { W = Wq; Wt = WqkvT;                        N = 2048; }
    else if (z == 1) { W = Wk; Wt = WqkvT + (size_t)2048 * 2048;  N = 512;  }
    else if (z == 2) { W = Wv; Wt = WqkvT + (size_t)2560 * 2048;  N = 512;  }
    else             { W = Wo; Wt = WoT;                          N = 2048; }
    if (blockIdx.x * 32 >= N) return;

    __shared__ float t[32][33];
    const int n0 = blockIdx.x * 32, k0 = blockIdx.y * 32;
    #pragma unroll
    for (int i = 0; i < 4; ++i)
        t[ty * 4 + i][tx] = W[(size_t)(k0 + ty * 4 + i) * N + n0 + tx];
    __syncthreads();
    #pragma unroll
    for (int i = 0; i < 4; ++i)
        Wt[(size_t)(n0 + ty * 4 + i) * 2048 + k0 + tx] = f2bf(t[tx][ty * 4 + i]);
}

// ---------------------------------------------------------------------------
// bf16 MFMA GEMM, B-transposed, async global_load_lds staging (m97 pattern).
// C(MxN fp32) = A(MxK bf16) @ Bt(NxK bf16)^T. 128x128 tile, BK=32.
// ---------------------------------------------------------------------------
__global__ __launch_bounds__(256) void gemm_bf16_bt(
    const unsigned short* __restrict__ A,
    const unsigned short* __restrict__ Bt,
    float* __restrict__ C, int M, int N, int K)
{
    __shared__ short As[128][32];
    __shared__ short Bs[128][32];

    const int tid  = threadIdx.x;
    const int lane = tid & 63;
    const int wave = tid >> 6;
    const int wm = (wave >> 1) * 64, wn = (wave & 1) * 64;
    const int m0 = blockIdx.y * 128, n0 = blockIdx.x * 128;

    f32x4 acc[4][4] = {};

    const int mrow = lane & 15;
    const int kq   = (lane >> 4) * 8;

    for (int k0 = 0; k0 < K; k0 += 32) {
        #pragma unroll
        for (int p = 0; p < 2; ++p) {
            int ci = tid + p * 256;           // 0..511, lane-contiguous per wave
            int row = ci >> 2;
            int q = (ci & 3) * 8;
            g2l16(&A [(size_t)(m0 + row) * K + k0 + q], (unsigned short*)&As[0][0] + ci * 8);
            g2l16(&Bt[(size_t)(n0 + row) * K + k0 + q], (unsigned short*)&Bs[0][0] + ci * 8);
        }
        __syncthreads();

        bf16x8 af[4], bfr[4];
        #pragma unroll
        for (int i = 0; i < 4; ++i)
            af[i] = *(const bf16x8*)&As[wm + i * 16 + mrow][kq];
        #pragma unroll
        for (int j = 0; j < 4; ++j)
            bfr[j] = *(const bf16x8*)&Bs[wn + j * 16 + mrow][kq];

        #pragma unroll
        for (int i = 0; i < 4; ++i)
            #pragma unroll
            for (int j = 0; j < 4; ++j)
                acc[i][j] = __builtin_amdgcn_mfma_f32_16x16x32_bf16(
                    af[i], bfr[j], acc[i][j], 0, 0, 0);
        __syncthreads();
    }

    #pragma unroll
    for (int i = 0; i < 4; ++i) {
        int grow = m0 + wm + i * 16 + (lane >> 4) * 4;
        #pragma unroll
        for (int j = 0; j < 4; ++j) {
            int gcol = n0 + wn + j * 16 + (lane & 15);
            #pragma unroll
            for (int rg = 0; rg < 4; ++rg)
                C[(size_t)(grow + rg) * N + gcol] = acc[i][j][rg];
        }
    }
}

// ---------------------------------------------------------------------------
// postproc: { rope q/k -> qk_bf bf16 } + { v transpose -> v_t bf16 }.
// ---------------------------------------------------------------------------
__global__ void postproc(const float* __restrict__ qkv,
                         unsigned short* __restrict__ qk_bf,
                         unsigned short* __restrict__ v_t)
{
    const int gb = blockIdx.x;
    if (gb < 10240) {
        const int r = gb >> 8;
        const int t = threadIdx.x & 31;
        const int row = (gb & 255) * 8 + (threadIdx.x >> 5);
        const int s = row & (SS - 1);

        const float* src = qkv + (size_t)row * NQKV + r * 64;
        unsigned short* dst = qk_bf + (size_t)row * QKW + r * 64;

        float x1 = src[t];
        float x2 = src[t + 32];
        float inv = powf(10000.f, -(float)t * (1.f / 32.f));
        float ang = (float)s * inv;
        float c, sn;
        sincosf(ang, &sn, &c);
        float scale = (r < 32) ? 0.125f : 1.0f;
        dst[t]      = f2bf((x1 * c - x2 * sn) * scale);
        dst[t + 32] = f2bf((x2 * c + x1 * sn) * scale);
    } else {
        __shared__ float tls[32][33];
        const int id = gb - 10240;
        const int cblk = id & 15;
        const int sblk = (id >> 4) & 31;
        const int b    = id >> 9;
        const int c0 = cblk * 32, s0 = sblk * 32;
        const int tx = threadIdx.x & 31, ty = threadIdx.x >> 5;
        #pragma unroll
        for (int i = 0; i < 4; ++i)
            tls[ty * 4 + i][tx] =
                qkv[(size_t)(b * SS + s0 + ty * 4 + i) * NQKV + 2560 + c0 + tx];
        __syncthreads();
        #pragma unroll
        for (int i = 0; i < 4; ++i)
            v_t[(size_t)(b * 512 + c0 + ty * 4 + i) * SS + s0 + tx] =
                f2bf(tls[tx][ty * 4 + i]);
    }
}

// ---------------------------------------------------------------------------
// MFMA flash attention, two-pass (R3-proven structure: LDS-staged tiles,
// 4-wave cooperative staging, wave w owns q-rows [w*16, w*16+16)).
// One block per (qtile64, h, b). Pass 1: l = sum exp(s+bias) via QK^T MFMA.
// Pass 2: recompute scores, w = relu(exp - c*l) -> bf16 -> PV MFMA; /l at end.
// ---------------------------------------------------------------------------
__global__ __launch_bounds__(256) void attn_mfma(
    const unsigned short* __restrict__ qk_bf,   // [2048][2560]
    const unsigned short* __restrict__ v_t,     // [1024][1024] (b*512+c rows)
    const float* __restrict__ bias_diag,
    const float* __restrict__ soff,
    unsigned short* __restrict__ AO)            // [2048][2048] bf16
{
    const int qt = 15 - (int)blockIdx.x;        // big tiles dispatched first
    const int h  = blockIdx.y;
    const int b  = blockIdx.z;
    const int kh = h >> 2;
    const int tid  = threadIdx.x;
    const int lane = tid & 63;
    const int wave = tid >> 6;
    const int quad = lane >> 4;
    const int l15  = lane & 15;
    const int kq   = quad * 8;
    const int q0   = qt * 64;

    __shared__ short Qs[64][72];
    __shared__ short Ks[64][72];
    __shared__ short Vt[64][72];
    __shared__ short Ws[64][72];
    __shared__ float bd_s[1024];

    for (int i = tid; i < 1024; i += 256) bd_s[i] = bias_diag[h * 1024 + i];

    {   // stage Q tile (rows q0.., cols h*64..)
        const unsigned short* Qg = qk_bf + (size_t)(b * SS + q0) * QKW + h * 64;
        #pragma unroll
        for (int p = 0; p < 2; ++p) {
            int t = tid + p * 256;
            int row = t >> 3, cq = (t & 7) * 8;
            *(int4*)&Qs[row][cq] = *(const int4*)&Qg[(size_t)row * QKW + cq];
        }
    }

    const int ntiles = qt + 1;
    const unsigned short* Kg = qk_bf + (size_t)(b * SS) * QKW + 2048 + kh * 64;
    const unsigned short* Vg = v_t + (size_t)(b * 512 + kh * 64) * SS;
    const int qrow = q0 + wave * 16 + quad * 4;   // first of this lane's 4 rows

    float lp[4] = {0.f, 0.f, 0.f, 0.f};

    // ---------------- pass 1: l ----------------
    for (int j = 0; j < ntiles; ++j) {
        __syncthreads();
        #pragma unroll
        for (int p = 0; p < 2; ++p) {
            int t = tid + p * 256;
            int row = t >> 3, cq = (t & 7) * 8;
            *(int4*)&Ks[row][cq] =
                *(const int4*)&Kg[(size_t)(j * 64 + row) * QKW + cq];
        }
        __syncthreads();

        f32x4 acc[4] = {};
        #pragma unroll
        for (int s = 0; s < 2; ++s) {
            bf16x8 af = *(const bf16x8*)&Qs[wave * 16 + l15][s * 32 + kq];
            #pragma unroll
            for (int nb = 0; nb < 4; ++nb) {
                bf16x8 bf = *(const bf16x8*)&Ks[nb * 16 + l15][s * 32 + kq];
                acc[nb] = __builtin_amdgcn_mfma_f32_16x16x32_bf16(
                    af, bf, acc[nb], 0, 0, 0);
            }
        }
        #pragma unroll
        for (int nb = 0; nb < 4; ++nb) {
            int kp = j * 64 + nb * 16 + l15;
            #pragma unroll
            for (int r = 0; r < 4; ++r) {
                int rel = qrow + r - kp;
                if (rel >= 0) lp[r] += __expf(acc[nb][r] + bd_s[rel]);
            }
        }
    }

    // reduce lp across the 16 lanes of each quad
    #pragma unroll
    for (int off = 1; off < 16; off <<= 1)
        #pragma unroll
        for (int r = 0; r < 4; ++r)
            lp[r] += __shfl_xor(lp[r], off, 64);

    float cl[4], invl[4];
    {
        float offa = fabsf(soff[h] + 1.f);
        #pragma unroll
        for (int r = 0; r < 4; ++r) {
            invl[r] = 1.f / lp[r];
            cl[r] = offa / (float)(qrow + r + 1) * lp[r];
        }
    }

    // ---------------- pass 2: output ----------------
    f32x4 oacc[4] = {};
    for (int j = 0; j < ntiles; ++j) {
        __syncthreads();
        #pragma unroll
        for (int p = 0; p < 2; ++p) {
            int t = tid + p * 256;
            int row = t >> 3, cq = (t & 7) * 8;
            *(int4*)&Ks[row][cq] =
                *(const int4*)&Kg[(size_t)(j * 64 + row) * QKW + cq];
            *(int4*)&Vt[row][cq] =
                *(const int4*)&Vg[(size_t)row * SS + j * 64 + cq];
        }
        __syncthreads();

        f32x4 acc[4] = {};
        #pragma unroll
        for (int s = 0; s < 2; ++s) {
            bf16x8 af = *(const bf16x8*)&Qs[wave * 16 + l15][s * 32 + kq];
            #pragma unroll
            for (int nb = 0; nb < 4; ++nb) {
                bf16x8 bf = *(const bf16x8*)&Ks[nb * 16 + l15][s * 32 + kq];
                acc[nb] = __builtin_amdgcn_mfma_f32_16x16x32_bf16(
                    af, bf, acc[nb], 0, 0, 0);
            }
        }
        // w = relu(exp(s) - c*l) in C-layout -> Ws (wave-private rows)
        #pragma unroll
        for (int nb = 0; nb < 4; ++nb) {
            int kp = j * 64 + nb * 16 + l15;
            #pragma unroll
            for (int r = 0; r < 4; ++r) {
                int rel = qrow + r - kp;
                float w = 0.f;
                if (rel >= 0)
                    w = fmaxf(__expf(acc[nb][r] + bd_s[rel]) - cl[r], 0.f);
                Ws[wave * 16 + quad * 4 + r][nb * 16 + l15] = (short)f2bf(w);
            }
        }
        // PV: A = Ws (q x kpos), B = Vt (d x kpos) -> C[q][d]
        #pragma unroll
        for (int s = 0; s < 2; ++s) {
            bf16x8 wf = *(const bf16x8*)&Ws[wave * 16 + l15][s * 32 + kq];
            #pragma unroll
            for (int nb = 0; nb < 4; ++nb) {
                bf16x8 vf = *(const bf16x8*)&Vt[nb * 16 + l15][s * 32 + kq];
                oacc[nb] = __builtin_amdgcn_mfma_f32_16x16x32_bf16(
                    wf, vf, oacc[nb], 0, 0, 0);
            }
        }
    }

    #pragma unroll
    for (int nb = 0; nb < 4; ++nb)
        #pragma unroll
        for (int r = 0; r < 4; ++r) {
            float o = oacc[nb][r] * invl[r];
            AO[(size_t)(b * SS + qrow + r) * 2048 + h * 64 + nb * 16 + l15] =
                f2bf(o);
        }
}

// ---------------------------------------------------------------------------
extern "C" void kernel_launch(void* const* d_in, const int* in_sizes, int n_in,
                              void* d_out, int out_size, void* d_ws, size_t ws_size,
                              hipStream_t stream)
{
    const float* hidden    = (const float*)d_in[0];
    const float* Wq        = (const float*)d_in[2];
    const float* Wk        = (const float*)d_in[3];
    const float* Wv        = (const float*)d_in[4];
    const float* Wo        = (const float*)d_in[5];
    const float* bias_diag = (const float*)d_in[6];
    const float* soff      = (const float*)d_in[7];
    float* out = (float*)d_out;

    // Workspace aliasing (54.5 MB, proven footprint):
    //  A [0,20.97M): hidden_bf(8.39)+WqkvT(12.58) --dead after QKV gemm-->
    //                qk_bf[0,10.49M) + v_t[10.49M,12.58M) + AO_bf[12.58M,20.97M)
    //  B [20.97M,29.36M): WoT
    //  C [29.36M,54.53M): qkv fp32(25.17M) --dead after postproc
    char* wsb = (char*)d_ws;
    unsigned short* hidden_bf = (unsigned short*)wsb;
    unsigned short* WqkvT     = (unsigned short*)(wsb + (size_t)8388608);
    unsigned short* qk_bf     = (unsigned short*)wsb;
    unsigned short* v_t       = (unsigned short*)(wsb + (size_t)10485760);
    unsigned short* AO_bf     = (unsigned short*)(wsb + (size_t)12582912);
    unsigned short* WoT       = (unsigned short*)(wsb + (size_t)20971520);
    float*          qkv       = (float*)(wsb + (size_t)29360128);

    // 1. weight transposes + hidden convert (one launch)
    prep<<<dim3(64, 64, 5), dim3(32, 8), 0, stream>>>(
        hidden, Wq, Wk, Wv, Wo, hidden_bf, WqkvT, WoT);

    // 2. fused QKV projection (fp32 out)
    gemm_bf16_bt<<<dim3(NQKV / 128, 2048 / 128), dim3(256), 0, stream>>>(
        hidden_bf, WqkvT, qkv, 2048, NQKV, 2048);

    // 3. rope+convert q,k and v transpose (one launch)
    postproc<<<dim3(11264), dim3(256), 0, stream>>>(qkv, qk_bf, v_t);

    // 4. two-pass LDS-staged MFMA attention (R3-proven) -> AO_bf
    attn_mfma<<<dim3(16, HH, BB), dim3(256), 0, stream>>>(
        qk_bf, v_t, bias_diag, soff, AO_bf);

    // 5. output projection
    gemm_bf16_bt<<<dim3(2048 / 128, 2048 / 128), dim3(256), 0, stream>>>(
        AO_bf, WoT, out, 2048, 2048, 2048);
}

// Round 10
// 288.922 us; speedup vs baseline: 1.2747x; 1.0475x over previous
//
#include <hip/hip_runtime.h>
#include <cstdint>
#include <cstddef>

// Problem constants
#define BB   2
#define SS   1024
#define HID  2048
#define HH   32
#define KVHH 8
#define DD   64
#define NQKV 3072   // fused QKV projection width: 2048 q + 512 k + 512 v
#define QKW  2560   // qk_bf row width: 2048 q + 512 k

typedef __attribute__((ext_vector_type(8))) short bf16x8;
typedef __attribute__((ext_vector_type(4))) float f32x4;

__device__ __forceinline__ unsigned short f2bf(float f) {
    unsigned int u = __float_as_uint(f);
    unsigned int r = (u + 0x7fffu + ((u >> 16) & 1u)) >> 16;
    return (unsigned short)r;
}

// async global->LDS 16B (wave-uniform LDS base + lane*16 layout required)
__device__ __forceinline__ void g2l16(const unsigned short* g, unsigned short* l) {
    __builtin_amdgcn_global_load_lds(
        (__attribute__((address_space(1))) void*)(unsigned short*)g,
        (__attribute__((address_space(3))) void*)l,
        16, 0, 0);
}

// ---------------------------------------------------------------------------
// prep (vectorized): z=0..3 weight transpose+convert (64x64 tiles, float4
// reads, ushort4 writes); z=4 hidden fp32->bf16 straight convert.
// block 256 flat.
// ---------------------------------------------------------------------------
__global__ __launch_bounds__(256) void prep(
    const float* __restrict__ hidden,
    const float* __restrict__ Wq, const float* __restrict__ Wk,
    const float* __restrict__ Wv, const float* __restrict__ Wo,
    unsigned short* __restrict__ hidden_bf,
    unsigned short* __restrict__ WqkvT,
    unsigned short* __restrict__ WoT)
{
    const int z   = blockIdx.z;
    const int tid = threadIdx.x;

    if (z == 4) {   // hidden convert, 2048x2048, 64x64 tile
        int r0 = blockIdx.y * 64, c0 = blockIdx.x * 64;
        #pragma unroll
        for (int p = 0; p < 4; ++p) {
            int f = tid + p * 256;            // 0..1023
            int row = r0 + (f >> 4), c4 = c0 + (f & 15) * 4;
            float4 v = *(const float4*)&hidden[(size_t)row * 2048 + c4];
            ushort4 o;
            o.x = f2bf(v.x); o.y = f2bf(v.y); o.z = f2bf(v.z); o.w = f2bf(v.w);
            *(ushort4*)&hidden_bf[(size_t)row * 2048 + c4] = o;
        }
        return;
    }

    const float* W;
    unsigned short* Wt;
    int N;
    if (z == 0)      { W = Wq; Wt = WqkvT;                        N = 2048; }
    else if (z == 1) { W = Wk; Wt = WqkvT + (size_t)2048 * 2048;  N = 512;  }
    else if (z == 2) { W = Wv; Wt = WqkvT + (size_t)2560 * 2048;  N = 512;  }
    else             { W = Wo; Wt = WoT;                          N = 2048; }
    if (blockIdx.x * 64 >= N) return;

    // 64x64 transpose tile via LDS, stride 68 (2-way bank alias only)
    __shared__ float t[64][68];
    const int n0 = blockIdx.x * 64, k0 = blockIdx.y * 64;
    #pragma unroll
    for (int p = 0; p < 4; ++p) {
        int f = tid + p * 256;
        int row = f >> 4, c4 = (f & 15) * 4;     // row=k_local, c4=n_local
        float4 v = *(const float4*)&W[(size_t)(k0 + row) * N + n0 + c4];
        t[row][c4 + 0] = v.x; t[row][c4 + 1] = v.y;
        t[row][c4 + 2] = v.z; t[row][c4 + 3] = v.w;
    }
    __syncthreads();
    #pragma unroll
    for (int p = 0; p < 4; ++p) {
        int f = tid + p * 256;
        int nrow = f >> 4, kc4 = (f & 15) * 4;   // output row=n, col=k
        ushort4 o;
        o.x = f2bf(t[kc4 + 0][nrow]);
        o.y = f2bf(t[kc4 + 1][nrow]);
        o.z = f2bf(t[kc4 + 2][nrow]);
        o.w = f2bf(t[kc4 + 3][nrow]);
        *(ushort4*)&Wt[(size_t)(n0 + nrow) * 2048 + k0 + kc4] = o;
    }
}

// ---------------------------------------------------------------------------
// bf16 MFMA GEMM, B-transposed, async global_load_lds staging.
// Tile 128(M) x 64(N), BK=32 -- doubled grid vs 128x128 for occupancy at
// the 2048-class shapes (m102: 1 blk/CU = 320 TF vs 4/CU = 833 TF).
// 256 threads = 4 waves in 2x2; wave computes 64m x 32n (4x2 fragments).
// ---------------------------------------------------------------------------
__global__ __launch_bounds__(256) void gemm_bf16_bt(
    const unsigned short* __restrict__ A,
    const unsigned short* __restrict__ Bt,
    float* __restrict__ C, int M, int N, int K)
{
    __shared__ short As[128][32];   // 8 KB
    __shared__ short Bs[64][32];    // 4 KB

    const int tid  = threadIdx.x;
    const int lane = tid & 63;
    const int wave = tid >> 6;
    const int wm = (wave >> 1) * 64, wn = (wave & 1) * 32;
    const int m0 = blockIdx.y * 128, n0 = blockIdx.x * 64;

    f32x4 acc[4][2] = {};

    const int mrow = lane & 15;
    const int kq   = (lane >> 4) * 8;

    for (int k0 = 0; k0 < K; k0 += 32) {
        #pragma unroll
        for (int p = 0; p < 2; ++p) {   // A: 512 x 16B chunks
            int ci = tid + p * 256;
            int row = ci >> 2;
            int q = (ci & 3) * 8;
            g2l16(&A[(size_t)(m0 + row) * K + k0 + q],
                  (unsigned short*)&As[0][0] + ci * 8);
        }
        {   // B: 256 x 16B chunks
            int ci = tid;
            int row = ci >> 2;
            int q = (ci & 3) * 8;
            g2l16(&Bt[(size_t)(n0 + row) * K + k0 + q],
                  (unsigned short*)&Bs[0][0] + ci * 8);
        }
        __syncthreads();

        bf16x8 af[4], bfr[2];
        #pragma unroll
        for (int i = 0; i < 4; ++i)
            af[i] = *(const bf16x8*)&As[wm + i * 16 + mrow][kq];
        #pragma unroll
        for (int j = 0; j < 2; ++j)
            bfr[j] = *(const bf16x8*)&Bs[wn + j * 16 + mrow][kq];

        #pragma unroll
        for (int i = 0; i < 4; ++i)
            #pragma unroll
            for (int j = 0; j < 2; ++j)
                acc[i][j] = __builtin_amdgcn_mfma_f32_16x16x32_bf16(
                    af[i], bfr[j], acc[i][j], 0, 0, 0);
        __syncthreads();
    }

    #pragma unroll
    for (int i = 0; i < 4; ++i) {
        int grow = m0 + wm + i * 16 + (lane >> 4) * 4;
        #pragma unroll
        for (int j = 0; j < 2; ++j) {
            int gcol = n0 + wn + j * 16 + (lane & 15);
            #pragma unroll
            for (int rg = 0; rg < 4; ++rg)
                C[(size_t)(grow + rg) * N + gcol] = acc[i][j][rg];
        }
    }
}

// ---------------------------------------------------------------------------
// postproc: { rope q/k -> qk_bf bf16 } + { v transpose -> v_t bf16 }.
// Fast-math transcendentals (__expf / __sinf / __cosf — HIP device intrinsics).
// ---------------------------------------------------------------------------
__global__ void postproc(const float* __restrict__ qkv,
                         unsigned short* __restrict__ qk_bf,
                         unsigned short* __restrict__ v_t)
{
    const int gb = blockIdx.x;
    if (gb < 10240) {
        const int r = gb >> 8;
        const int t = threadIdx.x & 31;
        const int row = (gb & 255) * 8 + (threadIdx.x >> 5);
        const int s = row & (SS - 1);

        const float* src = qkv + (size_t)row * NQKV + r * 64;
        unsigned short* dst = qk_bf + (size_t)row * QKW + r * 64;

        float x1 = src[t];
        float x2 = src[t + 32];
        // inv_freq = 10000^(-t/32) = e^(-t * ln(10000)/32)
        float inv = __expf(-(float)t * 0.28782313662425572f);
        float ang = (float)s * inv;
        float c  = __cosf(ang);
        float sn = __sinf(ang);
        float scale = (r < 32) ? 0.125f : 1.0f;
        dst[t]      = f2bf((x1 * c - x2 * sn) * scale);
        dst[t + 32] = f2bf((x2 * c + x1 * sn) * scale);
    } else {
        __shared__ float tls[32][33];
        const int id = gb - 10240;
        const int cblk = id & 15;
        const int sblk = (id >> 4) & 31;
        const int b    = id >> 9;
        const int c0 = cblk * 32, s0 = sblk * 32;
        const int tx = threadIdx.x & 31, ty = threadIdx.x >> 5;
        #pragma unroll
        for (int i = 0; i < 4; ++i)
            tls[ty * 4 + i][tx] =
                qkv[(size_t)(b * SS + s0 + ty * 4 + i) * NQKV + 2560 + c0 + tx];
        __syncthreads();
        #pragma unroll
        for (int i = 0; i < 4; ++i)
            v_t[(size_t)(b * 512 + c0 + ty * 4 + i) * SS + s0 + tx] =
                f2bf(tls[tx][ty * 4 + i]);
    }
}

// ---------------------------------------------------------------------------
// MFMA flash attention, two-pass (R3/R8-proven structure, unchanged).
// ---------------------------------------------------------------------------
__global__ __launch_bounds__(256) void attn_mfma(
    const unsigned short* __restrict__ qk_bf,   // [2048][2560]
    const unsigned short* __restrict__ v_t,     // [1024][1024]
    const float* __restrict__ bias_diag,
    const float* __restrict__ soff,
    unsigned short* __restrict__ AO)            // [2048][2048] bf16
{
    const int qt = 15 - (int)blockIdx.x;        // big tiles dispatched first
    const int h  = blockIdx.y;
    const int b  = blockIdx.z;
    const int kh = h >> 2;
    const int tid  = threadIdx.x;
    const int lane = tid & 63;
    const int wave = tid >> 6;
    const int quad = lane >> 4;
    const int l15  = lane & 15;
    const int kq   = quad * 8;
    const int q0   = qt * 64;

    __shared__ short Qs[64][72];
    __shared__ short Ks[64][72];
    __shared__ short Vt[64][72];
    __shared__ short Ws[64][72];
    __shared__ float bd_s[1024];

    for (int i = tid; i < 1024; i += 256) bd_s[i] = bias_diag[h * 1024 + i];

    {   // stage Q tile (rows q0.., cols h*64..)
        const unsigned short* Qg = qk_bf + (size_t)(b * SS + q0) * QKW + h * 64;
        #pragma unroll
        for (int p = 0; p < 2; ++p) {
            int t = tid + p * 256;
            int row = t >> 3, cq = (t & 7) * 8;
            *(int4*)&Qs[row][cq] = *(const int4*)&Qg[(size_t)row * QKW + cq];
        }
    }

    const int ntiles = qt + 1;
    const unsigned short* Kg = qk_bf + (size_t)(b * SS) * QKW + 2048 + kh * 64;
    const unsigned short* Vg = v_t + (size_t)(b * 512 + kh * 64) * SS;
    const int qrow = q0 + wave * 16 + quad * 4;   // first of this lane's 4 rows

    float lp[4] = {0.f, 0.f, 0.f, 0.f};

    // ---------------- pass 1: l ----------------
    for (int j = 0; j < ntiles; ++j) {
        __syncthreads();
        #pragma unroll
        for (int p = 0; p < 2; ++p) {
            int t = tid + p * 256;
            int row = t >> 3, cq = (t & 7) * 8;
            *(int4*)&Ks[row][cq] =
                *(const int4*)&Kg[(size_t)(j * 64 + row) * QKW + cq];
        }
        __syncthreads();

        f32x4 acc[4] = {};
        #pragma unroll
        for (int s = 0; s < 2; ++s) {
            bf16x8 af = *(const bf16x8*)&Qs[wave * 16 + l15][s * 32 + kq];
            #pragma unroll
            for (int nb = 0; nb < 4; ++nb) {
                bf16x8 bf = *(const bf16x8*)&Ks[nb * 16 + l15][s * 32 + kq];
                acc[nb] = __builtin_amdgcn_mfma_f32_16x16x32_bf16(
                    af, bf, acc[nb], 0, 0, 0);
            }
        }
        #pragma unroll
        for (int nb = 0; nb < 4; ++nb) {
            int kp = j * 64 + nb * 16 + l15;
            #pragma unroll
            for (int r = 0; r < 4; ++r) {
                int rel = qrow + r - kp;
                if (rel >= 0) lp[r] += __expf(acc[nb][r] + bd_s[rel]);
            }
        }
    }

    // reduce lp across the 16 lanes of each quad
    #pragma unroll
    for (int off = 1; off < 16; off <<= 1)
        #pragma unroll
        for (int r = 0; r < 4; ++r)
            lp[r] += __shfl_xor(lp[r], off, 64);

    float cl[4], invl[4];
    {
        float offa = fabsf(soff[h] + 1.f);
        #pragma unroll
        for (int r = 0; r < 4; ++r) {
            invl[r] = 1.f / lp[r];
            cl[r] = offa / (float)(qrow + r + 1) * lp[r];
        }
    }

    // ---------------- pass 2: output ----------------
    f32x4 oacc[4] = {};
    for (int j = 0; j < ntiles; ++j) {
        __syncthreads();
        #pragma unroll
        for (int p = 0; p < 2; ++p) {
            int t = tid + p * 256;
            int row = t >> 3, cq = (t & 7) * 8;
            *(int4*)&Ks[row][cq] =
                *(const int4*)&Kg[(size_t)(j * 64 + row) * QKW + cq];
            *(int4*)&Vt[row][cq] =
                *(const int4*)&Vg[(size_t)row * SS + j * 64 + cq];
        }
        __syncthreads();

        f32x4 acc[4] = {};
        #pragma unroll
        for (int s = 0; s < 2; ++s) {
            bf16x8 af = *(const bf16x8*)&Qs[wave * 16 + l15][s * 32 + kq];
            #pragma unroll
            for (int nb = 0; nb < 4; ++nb) {
                bf16x8 bf = *(const bf16x8*)&Ks[nb * 16 + l15][s * 32 + kq];
                acc[nb] = __builtin_amdgcn_mfma_f32_16x16x32_bf16(
                    af, bf, acc[nb], 0, 0, 0);
            }
        }
        // w = relu(exp(s) - c*l) in C-layout -> Ws (wave-private rows)
        #pragma unroll
        for (int nb = 0; nb < 4; ++nb) {
            int kp = j * 64 + nb * 16 + l15;
            #pragma unroll
            for (int r = 0; r < 4; ++r) {
                int rel = qrow + r - kp;
                float w = 0.f;
                if (rel >= 0)
                    w = fmaxf(__expf(acc[nb][r] + bd_s[rel]) - cl[r], 0.f);
                Ws[wave * 16 + quad * 4 + r][nb * 16 + l15] = (short)f2bf(w);
            }
        }
        // PV: A = Ws (q x kpos), B = Vt (d x kpos) -> C[q][d]
        #pragma unroll
        for (int s = 0; s < 2; ++s) {
            bf16x8 wf = *(const bf16x8*)&Ws[wave * 16 + l15][s * 32 + kq];
            #pragma unroll
            for (int nb = 0; nb < 4; ++nb) {
                bf16x8 vf = *(const bf16x8*)&Vt[nb * 16 + l15][s * 32 + kq];
                oacc[nb] = __builtin_amdgcn_mfma_f32_16x16x32_bf16(
                    wf, vf, oacc[nb], 0, 0, 0);
            }
        }
    }

    #pragma unroll
    for (int nb = 0; nb < 4; ++nb)
        #pragma unroll
        for (int r = 0; r < 4; ++r) {
            float o = oacc[nb][r] * invl[r];
            AO[(size_t)(b * SS + qrow + r) * 2048 + h * 64 + nb * 16 + l15] =
                f2bf(o);
        }
}

// ---------------------------------------------------------------------------
extern "C" void kernel_launch(void* const* d_in, const int* in_sizes, int n_in,
                              void* d_out, int out_size, void* d_ws, size_t ws_size,
                              hipStream_t stream)
{
    const float* hidden    = (const float*)d_in[0];
    const float* Wq        = (const float*)d_in[2];
    const float* Wk        = (const float*)d_in[3];
    const float* Wv        = (const float*)d_in[4];
    const float* Wo        = (const float*)d_in[5];
    const float* bias_diag = (const float*)d_in[6];
    const float* soff      = (const float*)d_in[7];
    float* out = (float*)d_out;

    // Workspace aliasing (54.5 MB, proven footprint):
    //  A [0,20.97M): hidden_bf(8.39)+WqkvT(12.58) --dead after QKV gemm-->
    //                qk_bf[0,10.49M) + v_t[10.49M,12.58M) + AO_bf[12.58M,20.97M)
    //  B [20.97M,29.36M): WoT
    //  C [29.36M,54.53M): qkv fp32(25.17M) --dead after postproc
    char* wsb = (char*)d_ws;
    unsigned short* hidden_bf = (unsigned short*)wsb;
    unsigned short* WqkvT     = (unsigned short*)(wsb + (size_t)8388608);
    unsigned short* qk_bf     = (unsigned short*)wsb;
    unsigned short* v_t       = (unsigned short*)(wsb + (size_t)10485760);
    unsigned short* AO_bf     = (unsigned short*)(wsb + (size_t)12582912);
    unsigned short* WoT       = (unsigned short*)(wsb + (size_t)20971520);
    float*          qkv       = (float*)(wsb + (size_t)29360128);

    // 1. weight transposes + hidden convert (one launch, vectorized)
    prep<<<dim3(32, 32, 5), dim3(256), 0, stream>>>(
        hidden, Wq, Wk, Wv, Wo, hidden_bf, WqkvT, WoT);

    // 2. fused QKV projection (fp32 out): 128x64 tiles -> 768 blocks (3/CU)
    gemm_bf16_bt<<<dim3(NQKV / 64, 2048 / 128), dim3(256), 0, stream>>>(
        hidden_bf, WqkvT, qkv, 2048, NQKV, 2048);

    // 3. rope+convert q,k and v transpose (one launch)
    postproc<<<dim3(11264), dim3(256), 0, stream>>>(qkv, qk_bf, v_t);

    // 4. two-pass LDS-staged MFMA attention -> AO_bf
    attn_mfma<<<dim3(16, HH, BB), dim3(256), 0, stream>>>(
        qk_bf, v_t, bias_diag, soff, AO_bf);

    // 5. output projection: 128x64 tiles -> 512 blocks (2/CU)
    gemm_bf16_bt<<<dim3(2048 / 64, 2048 / 128), dim3(256), 0, stream>>>(
        AO_bf, WoT, out, 2048, 2048, 2048);
}

// Round 11
// 280.522 us; speedup vs baseline: 1.3128x; 1.0299x over previous
//
#include <hip/hip_runtime.h>
#include <cstdint>
#include <cstddef>

// Problem constants
#define BB   2
#define SS   1024
#define HID  2048
#define HH   32
#define KVHH 8
#define DD   64
#define NQKV 3072   // fused QKV projection width: 2048 q + 512 k + 512 v
#define QKW  2560   // qk_bf row width: 2048 q + 512 k

typedef __attribute__((ext_vector_type(8))) short bf16x8;
typedef __attribute__((ext_vector_type(4))) float f32x4;

__device__ __forceinline__ unsigned short f2bf(float f) {
    unsigned int u = __float_as_uint(f);
    unsigned int r = (u + 0x7fffu + ((u >> 16) & 1u)) >> 16;
    return (unsigned short)r;
}

// async global->LDS 16B (wave-uniform LDS base + lane*16 layout required)
__device__ __forceinline__ void g2l16(const unsigned short* g, unsigned short* l) {
    __builtin_amdgcn_global_load_lds(
        (__attribute__((address_space(1))) void*)(unsigned short*)g,
        (__attribute__((address_space(3))) void*)l,
        16, 0, 0);
}

// ---------------------------------------------------------------------------
// prep (vectorized): z=0..3 weight transpose+convert (64x64 tiles, float4
// reads, ushort4 writes); z=4 hidden fp32->bf16 straight convert.
// ---------------------------------------------------------------------------
__global__ __launch_bounds__(256) void prep(
    const float* __restrict__ hidden,
    const float* __restrict__ Wq, const float* __restrict__ Wk,
    const float* __restrict__ Wv, const float* __restrict__ Wo,
    unsigned short* __restrict__ hidden_bf,
    unsigned short* __restrict__ WqkvT,
    unsigned short* __restrict__ WoT)
{
    const int z   = blockIdx.z;
    const int tid = threadIdx.x;

    if (z == 4) {   // hidden convert, 2048x2048, 64x64 tile
        int r0 = blockIdx.y * 64, c0 = blockIdx.x * 64;
        #pragma unroll
        for (int p = 0; p < 4; ++p) {
            int f = tid + p * 256;            // 0..1023
            int row = r0 + (f >> 4), c4 = c0 + (f & 15) * 4;
            float4 v = *(const float4*)&hidden[(size_t)row * 2048 + c4];
            ushort4 o;
            o.x = f2bf(v.x); o.y = f2bf(v.y); o.z = f2bf(v.z); o.w = f2bf(v.w);
            *(ushort4*)&hidden_bf[(size_t)row * 2048 + c4] = o;
        }
        return;
    }

    const float* W;
    unsigned short* Wt;
    int N;
    if (z == 0)      { W = Wq; Wt = WqkvT;                        N = 2048; }
    else if (z == 1) { W = Wk; Wt = WqkvT + (size_t)2048 * 2048;  N = 512;  }
    else if (z == 2) { W = Wv; Wt = WqkvT + (size_t)2560 * 2048;  N = 512;  }
    else             { W = Wo; Wt = WoT;                          N = 2048; }
    if (blockIdx.x * 64 >= N) return;

    // 64x64 transpose tile via LDS, stride 68 (2-way bank alias only)
    __shared__ float t[64][68];
    const int n0 = blockIdx.x * 64, k0 = blockIdx.y * 64;
    #pragma unroll
    for (int p = 0; p < 4; ++p) {
        int f = tid + p * 256;
        int row = f >> 4, c4 = (f & 15) * 4;     // row=k_local, c4=n_local
        float4 v = *(const float4*)&W[(size_t)(k0 + row) * N + n0 + c4];
        t[row][c4 + 0] = v.x; t[row][c4 + 1] = v.y;
        t[row][c4 + 2] = v.z; t[row][c4 + 3] = v.w;
    }
    __syncthreads();
    #pragma unroll
    for (int p = 0; p < 4; ++p) {
        int f = tid + p * 256;
        int nrow = f >> 4, kc4 = (f & 15) * 4;   // output row=n, col=k
        ushort4 o;
        o.x = f2bf(t[kc4 + 0][nrow]);
        o.y = f2bf(t[kc4 + 1][nrow]);
        o.z = f2bf(t[kc4 + 2][nrow]);
        o.w = f2bf(t[kc4 + 3][nrow]);
        *(ushort4*)&Wt[(size_t)(n0 + nrow) * 2048 + k0 + kc4] = o;
    }
}

// ---------------------------------------------------------------------------
// Fused QKV GEMM + rope/V-transpose epilogue. Tile 128(M) x 64(N), BK=32,
// async global_load_lds staging. Grid (48, 16): bx<32 -> q head bx;
// bx 32..39 -> k head bx-32; bx 40..47 -> v head bx-40.
// Epilogue: C tile -> LDS (fp32, stride 65) -> rope'd bf16 into qk_bf
// (q scaled 0.125) or transposed bf16 into v_t. No fp32 qkv intermediate.
// ---------------------------------------------------------------------------
__global__ __launch_bounds__(256) void gemm_qkv_fused(
    const unsigned short* __restrict__ A,     // hidden_bf [2048][2048]
    const unsigned short* __restrict__ Bt,    // WqkvT [3072][2048]
    unsigned short* __restrict__ qk_bf,       // [2048][2560]
    unsigned short* __restrict__ v_t)         // [1024][1024]
{
    __shared__ short As[128][32];   // 8 KB
    __shared__ short Bs[64][32];    // 4 KB
    __shared__ float Ct[128][65];   // 32.5 KB, stride 65: <=4-way alias on
                                    // the transpose-read, 2-way on rope-read

    const int tid  = threadIdx.x;
    const int lane = tid & 63;
    const int wave = tid >> 6;
    const int wm = (wave >> 1) * 64, wn = (wave & 1) * 32;
    const int m0 = blockIdx.y * 128, n0 = blockIdx.x * 64;
    const int K = 2048;

    f32x4 acc[4][2] = {};

    const int mrow = lane & 15;
    const int kq   = (lane >> 4) * 8;
    const int quad = lane >> 4;
    const int l15  = lane & 15;

    for (int k0 = 0; k0 < K; k0 += 32) {
        #pragma unroll
        for (int p = 0; p < 2; ++p) {   // A: 512 x 16B chunks
            int ci = tid + p * 256;
            int row = ci >> 2;
            int q = (ci & 3) * 8;
            g2l16(&A[(size_t)(m0 + row) * K + k0 + q],
                  (unsigned short*)&As[0][0] + ci * 8);
        }
        {   // B: 256 x 16B chunks
            int ci = tid;
            int row = ci >> 2;
            int q = (ci & 3) * 8;
            g2l16(&Bt[(size_t)(n0 + row) * K + k0 + q],
                  (unsigned short*)&Bs[0][0] + ci * 8);
        }
        __syncthreads();

        bf16x8 af[4], bfr[2];
        #pragma unroll
        for (int i = 0; i < 4; ++i)
            af[i] = *(const bf16x8*)&As[wm + i * 16 + mrow][kq];
        #pragma unroll
        for (int j = 0; j < 2; ++j)
            bfr[j] = *(const bf16x8*)&Bs[wn + j * 16 + mrow][kq];

        #pragma unroll
        for (int i = 0; i < 4; ++i)
            #pragma unroll
            for (int j = 0; j < 2; ++j)
                acc[i][j] = __builtin_amdgcn_mfma_f32_16x16x32_bf16(
                    af[i], bfr[j], acc[i][j], 0, 0, 0);
        __syncthreads();
    }

    // ---- epilogue: fragments -> LDS fp32 tile ----
    #pragma unroll
    for (int i = 0; i < 4; ++i)
        #pragma unroll
        for (int j = 0; j < 2; ++j)
            #pragma unroll
            for (int rg = 0; rg < 4; ++rg)
                Ct[wm + i * 16 + quad * 4 + rg][wn + j * 16 + l15] = acc[i][j][rg];
    __syncthreads();

    const int bx = blockIdx.x;
    const int b  = m0 >> 10;           // batch (tile never straddles: m0 % 128 == 0)
    const int s0 = m0 & 1023;

    if (bx < 40) {
        // rope q/k: qk_bf col base = bx*64 (q: 0..2047; k: 2048 + (bx-32)*64)
        const int hc = bx * 64;
        const float scale = (bx < 32) ? 0.125f : 1.0f;
        #pragma unroll
        for (int p = 0; p < 4; ++p) {
            int idx = tid + p * 256;          // 128 rows x 8 t-groups
            int row = idx >> 3, t0 = (idx & 7) * 4;
            int s = s0 + row;
            ushort4 o1, o2;
            #pragma unroll
            for (int k = 0; k < 4; ++k) {
                int t = t0 + k;
                float x1 = Ct[row][t];
                float x2 = Ct[row][t + 32];
                // inv_freq = 10000^(-t/32) = e^(-t*ln(10000)/32)
                float inv = __expf(-(float)t * 0.28782313662425572f);
                float ang = (float)s * inv;
                float c  = __cosf(ang);
                float sn = __sinf(ang);
                ((unsigned short*)&o1)[k] = f2bf((x1 * c - x2 * sn) * scale);
                ((unsigned short*)&o2)[k] = f2bf((x2 * c + x1 * sn) * scale);
            }
            unsigned short* dst = qk_bf + (size_t)(m0 + row) * QKW + hc;
            *(ushort4*)&dst[t0]      = o1;
            *(ushort4*)&dst[t0 + 32] = o2;
        }
    } else {
        // v transpose: v_t[(b*512 + (bx-40)*64 + c)][s0 + srow]
        const int vb = b * 512 + (bx - 40) * 64;
        #pragma unroll
        for (int p = 0; p < 8; ++p) {
            int idx = tid + p * 256;          // 64 c x 32 s-groups
            int c = idx >> 5, srow = (idx & 31) * 4;
            ushort4 o;
            #pragma unroll
            for (int k = 0; k < 4; ++k)
                ((unsigned short*)&o)[k] = f2bf(Ct[srow + k][c]);
            *(ushort4*)&v_t[(size_t)(vb + c) * 1024 + s0 + srow] = o;
        }
    }
}

// ---------------------------------------------------------------------------
// bf16 MFMA GEMM, B-transposed (Wo projection). Tile 128x64, BK=32.
// ---------------------------------------------------------------------------
__global__ __launch_bounds__(256) void gemm_bf16_bt(
    const unsigned short* __restrict__ A,
    const unsigned short* __restrict__ Bt,
    float* __restrict__ C, int M, int N, int K)
{
    __shared__ short As[128][32];   // 8 KB
    __shared__ short Bs[64][32];    // 4 KB

    const int tid  = threadIdx.x;
    const int lane = tid & 63;
    const int wave = tid >> 6;
    const int wm = (wave >> 1) * 64, wn = (wave & 1) * 32;
    const int m0 = blockIdx.y * 128, n0 = blockIdx.x * 64;

    f32x4 acc[4][2] = {};

    const int mrow = lane & 15;
    const int kq   = (lane >> 4) * 8;

    for (int k0 = 0; k0 < K; k0 += 32) {
        #pragma unroll
        for (int p = 0; p < 2; ++p) {   // A: 512 x 16B chunks
            int ci = tid + p * 256;
            int row = ci >> 2;
            int q = (ci & 3) * 8;
            g2l16(&A[(size_t)(m0 + row) * K + k0 + q],
                  (unsigned short*)&As[0][0] + ci * 8);
        }
        {   // B: 256 x 16B chunks
            int ci = tid;
            int row = ci >> 2;
            int q = (ci & 3) * 8;
            g2l16(&Bt[(size_t)(n0 + row) * K + k0 + q],
                  (unsigned short*)&Bs[0][0] + ci * 8);
        }
        __syncthreads();

        bf16x8 af[4], bfr[2];
        #pragma unroll
        for (int i = 0; i < 4; ++i)
            af[i] = *(const bf16x8*)&As[wm + i * 16 + mrow][kq];
        #pragma unroll
        for (int j = 0; j < 2; ++j)
            bfr[j] = *(const bf16x8*)&Bs[wn + j * 16 + mrow][kq];

        #pragma unroll
        for (int i = 0; i < 4; ++i)
            #pragma unroll
            for (int j = 0; j < 2; ++j)
                acc[i][j] = __builtin_amdgcn_mfma_f32_16x16x32_bf16(
                    af[i], bfr[j], acc[i][j], 0, 0, 0);
        __syncthreads();
    }

    #pragma unroll
    for (int i = 0; i < 4; ++i) {
        int grow = m0 + wm + i * 16 + (lane >> 4) * 4;
        #pragma unroll
        for (int j = 0; j < 2; ++j) {
            int gcol = n0 + wn + j * 16 + (lane & 15);
            #pragma unroll
            for (int rg = 0; rg < 4; ++rg)
                C[(size_t)(grow + rg) * N + gcol] = acc[i][j][rg];
        }
    }
}

// ---------------------------------------------------------------------------
// MFMA flash attention, two-pass (R3/R8-proven structure, unchanged).
// ---------------------------------------------------------------------------
__global__ __launch_bounds__(256) void attn_mfma(
    const unsigned short* __restrict__ qk_bf,   // [2048][2560]
    const unsigned short* __restrict__ v_t,     // [1024][1024]
    const float* __restrict__ bias_diag,
    const float* __restrict__ soff,
    unsigned short* __restrict__ AO)            // [2048][2048] bf16
{
    const int qt = 15 - (int)blockIdx.x;        // big tiles dispatched first
    const int h  = blockIdx.y;
    const int b  = blockIdx.z;
    const int kh = h >> 2;
    const int tid  = threadIdx.x;
    const int lane = tid & 63;
    const int wave = tid >> 6;
    const int quad = lane >> 4;
    const int l15  = lane & 15;
    const int kq   = quad * 8;
    const int q0   = qt * 64;

    __shared__ short Qs[64][72];
    __shared__ short Ks[64][72];
    __shared__ short Vt[64][72];
    __shared__ short Ws[64][72];
    __shared__ float bd_s[1024];

    for (int i = tid; i < 1024; i += 256) bd_s[i] = bias_diag[h * 1024 + i];

    {   // stage Q tile (rows q0.., cols h*64..)
        const unsigned short* Qg = qk_bf + (size_t)(b * SS + q0) * QKW + h * 64;
        #pragma unroll
        for (int p = 0; p < 2; ++p) {
            int t = tid + p * 256;
            int row = t >> 3, cq = (t & 7) * 8;
            *(int4*)&Qs[row][cq] = *(const int4*)&Qg[(size_t)row * QKW + cq];
        }
    }

    const int ntiles = qt + 1;
    const unsigned short* Kg = qk_bf + (size_t)(b * SS) * QKW + 2048 + kh * 64;
    const unsigned short* Vg = v_t + (size_t)(b * 512 + kh * 64) * SS;
    const int qrow = q0 + wave * 16 + quad * 4;   // first of this lane's 4 rows

    float lp[4] = {0.f, 0.f, 0.f, 0.f};

    // ---------------- pass 1: l ----------------
    for (int j = 0; j < ntiles; ++j) {
        __syncthreads();
        #pragma unroll
        for (int p = 0; p < 2; ++p) {
            int t = tid + p * 256;
            int row = t >> 3, cq = (t & 7) * 8;
            *(int4*)&Ks[row][cq] =
                *(const int4*)&Kg[(size_t)(j * 64 + row) * QKW + cq];
        }
        __syncthreads();

        f32x4 acc[4] = {};
        #pragma unroll
        for (int s = 0; s < 2; ++s) {
            bf16x8 af = *(const bf16x8*)&Qs[wave * 16 + l15][s * 32 + kq];
            #pragma unroll
            for (int nb = 0; nb < 4; ++nb) {
                bf16x8 bf = *(const bf16x8*)&Ks[nb * 16 + l15][s * 32 + kq];
                acc[nb] = __builtin_amdgcn_mfma_f32_16x16x32_bf16(
                    af, bf, acc[nb], 0, 0, 0);
            }
        }
        #pragma unroll
        for (int nb = 0; nb < 4; ++nb) {
            int kp = j * 64 + nb * 16 + l15;
            #pragma unroll
            for (int r = 0; r < 4; ++r) {
                int rel = qrow + r - kp;
                if (rel >= 0) lp[r] += __expf(acc[nb][r] + bd_s[rel]);
            }
        }
    }

    // reduce lp across the 16 lanes of each quad
    #pragma unroll
    for (int off = 1; off < 16; off <<= 1)
        #pragma unroll
        for (int r = 0; r < 4; ++r)
            lp[r] += __shfl_xor(lp[r], off, 64);

    float cl[4], invl[4];
    {
        float offa = fabsf(soff[h] + 1.f);
        #pragma unroll
        for (int r = 0; r < 4; ++r) {
            invl[r] = 1.f / lp[r];
            cl[r] = offa / (float)(qrow + r + 1) * lp[r];
        }
    }

    // ---------------- pass 2: output ----------------
    f32x4 oacc[4] = {};
    for (int j = 0; j < ntiles; ++j) {
        __syncthreads();
        #pragma unroll
        for (int p = 0; p < 2; ++p) {
            int t = tid + p * 256;
            int row = t >> 3, cq = (t & 7) * 8;
            *(int4*)&Ks[row][cq] =
                *(const int4*)&Kg[(size_t)(j * 64 + row) * QKW + cq];
            *(int4*)&Vt[row][cq] =
                *(const int4*)&Vg[(size_t)row * SS + j * 64 + cq];
        }
        __syncthreads();

        f32x4 acc[4] = {};
        #pragma unroll
        for (int s = 0; s < 2; ++s) {
            bf16x8 af = *(const bf16x8*)&Qs[wave * 16 + l15][s * 32 + kq];
            #pragma unroll
            for (int nb = 0; nb < 4; ++nb) {
                bf16x8 bf = *(const bf16x8*)&Ks[nb * 16 + l15][s * 32 + kq];
                acc[nb] = __builtin_amdgcn_mfma_f32_16x16x32_bf16(
                    af, bf, acc[nb], 0, 0, 0);
            }
        }
        // w = relu(exp(s) - c*l) in C-layout -> Ws (wave-private rows)
        #pragma unroll
        for (int nb = 0; nb < 4; ++nb) {
            int kp = j * 64 + nb * 16 + l15;
            #pragma unroll
            for (int r = 0; r < 4; ++r) {
                int rel = qrow + r - kp;
                float w = 0.f;
                if (rel >= 0)
                    w = fmaxf(__expf(acc[nb][r] + bd_s[rel]) - cl[r], 0.f);
                Ws[wave * 16 + quad * 4 + r][nb * 16 + l15] = (short)f2bf(w);
            }
        }
        // PV: A = Ws (q x kpos), B = Vt (d x kpos) -> C[q][d]
        #pragma unroll
        for (int s = 0; s < 2; ++s) {
            bf16x8 wf = *(const bf16x8*)&Ws[wave * 16 + l15][s * 32 + kq];
            #pragma unroll
            for (int nb = 0; nb < 4; ++nb) {
                bf16x8 vf = *(const bf16x8*)&Vt[nb * 16 + l15][s * 32 + kq];
                oacc[nb] = __builtin_amdgcn_mfma_f32_16x16x32_bf16(
                    wf, vf, oacc[nb], 0, 0, 0);
            }
        }
    }

    #pragma unroll
    for (int nb = 0; nb < 4; ++nb)
        #pragma unroll
        for (int r = 0; r < 4; ++r) {
            float o = oacc[nb][r] * invl[r];
            AO[(size_t)(b * SS + qrow + r) * 2048 + h * 64 + nb * 16 + l15] =
                f2bf(o);
        }
}

// ---------------------------------------------------------------------------
extern "C" void kernel_launch(void* const* d_in, const int* in_sizes, int n_in,
                              void* d_out, int out_size, void* d_ws, size_t ws_size,
                              hipStream_t stream)
{
    const float* hidden    = (const float*)d_in[0];
    const float* Wq        = (const float*)d_in[2];
    const float* Wk        = (const float*)d_in[3];
    const float* Wv        = (const float*)d_in[4];
    const float* Wo        = (const float*)d_in[5];
    const float* bias_diag = (const float*)d_in[6];
    const float* soff      = (const float*)d_in[7];
    float* out = (float*)d_out;

    // Workspace aliasing:
    //  A [0,20.97M): hidden_bf(8.39) + WqkvT(12.58) -- inputs of QKV gemm.
    //                AO_bf at [12.58M,20.97M)?  NO -- WqkvT occupies it.
    //                AO_bf lives at [12.58M..) only AFTER WqkvT is dead:
    //                attention writes AO_bf after the QKV gemm has consumed
    //                WqkvT, so the overlap [12.58M,20.97M) is safe.
    //  B [20.97M,29.36M): WoT
    //  C [29.36M,41.94M): qk_bf(10.49M) + v_t(2.10M)  (written by fused gemm,
    //                     disjoint from its inputs in region A)
    char* wsb = (char*)d_ws;
    unsigned short* hidden_bf = (unsigned short*)wsb;
    unsigned short* WqkvT     = (unsigned short*)(wsb + (size_t)8388608);
    unsigned short* AO_bf     = (unsigned short*)(wsb + (size_t)12582912);
    unsigned short* WoT       = (unsigned short*)(wsb + (size_t)20971520);
    unsigned short* qk_bf     = (unsigned short*)(wsb + (size_t)29360128);
    unsigned short* v_t       = (unsigned short*)(wsb + (size_t)29360128 + (size_t)2048 * 2560 * 2);

    // 1. weight transposes + hidden convert (one launch, vectorized)
    prep<<<dim3(32, 32, 5), dim3(256), 0, stream>>>(
        hidden, Wq, Wk, Wv, Wo, hidden_bf, WqkvT, WoT);

    // 2. fused QKV projection + rope/V-transpose epilogue (768 blocks, 3/CU)
    gemm_qkv_fused<<<dim3(48, 16), dim3(256), 0, stream>>>(
        hidden_bf, WqkvT, qk_bf, v_t);

    // 3. two-pass LDS-staged MFMA attention -> AO_bf
    attn_mfma<<<dim3(16, HH, BB), dim3(256), 0, stream>>>(
        qk_bf, v_t, bias_diag, soff, AO_bf);

    // 4. output projection (512 blocks, 2/CU)
    gemm_bf16_bt<<<dim3(2048 / 64, 2048 / 128), dim3(256), 0, stream>>>(
        AO_bf, WoT, out, 2048, 2048, 2048);
}